// Round 3
// baseline (1261.709 us; speedup 1.0000x reference)
//
#include <hip/hip_runtime.h>
#include <hip/hip_bf16.h>
#include <math.h>

#define D_MODEL 1024
#define D_INNER 2048
#define NSTATE  16
#define BATCH   4
#define SEQ     4096
#define MTOT    (BATCH*SEQ)      // 16384
#define SDT     2176             // dtBC row stride: 2048 dt | 16 B | 16 C | 96 pad
#define NCAT    2176             // padded N of concat weight
#define NCHUNK  16
#define CLEN    (SEQ/NCHUNK)     // 256
#define N1      (2*D_INNER)      // 4096

typedef __attribute__((ext_vector_type(8))) __bf16 bf16x8;
typedef __attribute__((ext_vector_type(4))) float f32x4;

__device__ __forceinline__ float b2f(unsigned short u){
  return __uint_as_float(((unsigned int)u) << 16);
}
__device__ __forceinline__ unsigned short f2b(float f){
  unsigned int u = __float_as_uint(f);
  u = (u + 0x7FFFu + ((u >> 16) & 1u)) >> 16;   // RNE
  return (unsigned short)u;
}
__device__ __forceinline__ float softplus_f(float x){
  float r = log1pf(__expf(-fabsf(x)));
  return x > 0.f ? x + r : r;
}

// ---- f32 -> bf16 convert (4 elems/thread) ----
__global__ void cvt_f2b_kernel(const float* __restrict__ src,
                               unsigned short* __restrict__ dst){
  int i = (blockIdx.x * 256 + threadIdx.x) * 4;
  float4 v = *(const float4*)(src + i);
  ushort2 lo = {f2b(v.x), f2b(v.y)};
  ushort2 hi = {f2b(v.z), f2b(v.w)};
  *(ushort2*)(dst + i)     = lo;
  *(ushort2*)(dst + i + 2) = hi;
}

// ---- build Wcat(bf16) = [W_dt(2048); W_B(16); W_C(16); zeros(96)] : 2176x2048 ----
__global__ void concat_w_kernel(const float* __restrict__ Wdt,
                                const float* __restrict__ WB,
                                const float* __restrict__ WC,
                                unsigned short* __restrict__ Wcat){
  int idx = blockIdx.x * 256 + threadIdx.x;   // 4-elem granularity
  int row = idx >> 9;                         // 2048 cols = 512 quads/row
  int q   = idx & 511;
  float4 v;
  if      (row < 2048) v = *(const float4*)(Wdt + ((size_t)row * 2048 + q * 4));
  else if (row < 2064) v = *(const float4*)(WB  + ((size_t)(row - 2048) * 2048 + q * 4));
  else if (row < 2080) v = *(const float4*)(WC  + ((size_t)(row - 2064) * 2048 + q * 4));
  else                 v = make_float4(0.f, 0.f, 0.f, 0.f);
  unsigned short* p = Wcat + (size_t)idx * 4;
  *(ushort2*)(p)     = (ushort2){f2b(v.x), f2b(v.y)};
  *(ushort2*)(p + 2) = (ushort2){f2b(v.z), f2b(v.w)};
}

// ---- GEMM: C[M,N] = A[M,K] @ W[N,K]^T, bf16 MFMA, fp32 acc, fused epilogues ----
// AF32: A is f32 (convert during LDS staging); else A is bf16.
// MODE 0: split cols -> o0=xs (n<2048), o1=z (n>=2048)   [bf16 out]
// MODE 1: n<2048 -> softplus(v + bias[n]); store stride SDT into o0=dtBC [bf16]
// MODE 2: v * sigmoid(bias[0]); store f32 into of (row stride D_MODEL)
template<int MODE, int AF32>
__global__ __launch_bounds__(256) void gemm_bt(
    const void* __restrict__ Av,
    const unsigned short* __restrict__ W,
    unsigned short* __restrict__ o0,
    unsigned short* __restrict__ o1,
    float* __restrict__ of,
    const float* __restrict__ bias,
    int K)
{
  const int bm = blockIdx.y, bn = blockIdx.x;
  const int tid = threadIdx.x;
  const int lane = tid & 63;
  const int wid = tid >> 6;
  const int wr = wid >> 1, wc = wid & 1;

  __shared__ unsigned short sA[128 * 72];   // 128 rows x 64 cols, stride 72 (pad)
  __shared__ unsigned short sB[128 * 72];

  f32x4 acc[4][4];
  #pragma unroll
  for (int i = 0; i < 4; i++)
    #pragma unroll
    for (int j = 0; j < 4; j++) acc[i][j] = (f32x4){0.f, 0.f, 0.f, 0.f};

  const int lrow = tid >> 3;   // 0..31
  const int lch  = tid & 7;    // 8-elem chunk within 64-col k-tile
  const unsigned short* Ab = (const unsigned short*)Av + (size_t)(bm * 128 + lrow) * K + lch * 8;
  const float*          Af = (const float*)Av          + (size_t)(bm * 128 + lrow) * K + lch * 8;
  const unsigned short* Wp = W + (size_t)(bn * 128 + lrow) * K + lch * 8;

  for (int k0 = 0; k0 < K; k0 += 64) {
    #pragma unroll
    for (int i = 0; i < 4; i++) {
      uint4 va;
      if (AF32) {
        float4 f0 = *(const float4*)(Af + (size_t)(i * 32) * K + k0);
        float4 f1 = *(const float4*)(Af + (size_t)(i * 32) * K + k0 + 4);
        va.x = (unsigned int)f2b(f0.x) | ((unsigned int)f2b(f0.y) << 16);
        va.y = (unsigned int)f2b(f0.z) | ((unsigned int)f2b(f0.w) << 16);
        va.z = (unsigned int)f2b(f1.x) | ((unsigned int)f2b(f1.y) << 16);
        va.w = (unsigned int)f2b(f1.z) | ((unsigned int)f2b(f1.w) << 16);
      } else {
        va = *(const uint4*)(Ab + (size_t)(i * 32) * K + k0);
      }
      uint4 vb = *(const uint4*)(Wp + (size_t)(i * 32) * K + k0);
      *(uint4*)&sA[(lrow + i * 32) * 72 + lch * 8] = va;
      *(uint4*)&sB[(lrow + i * 32) * 72 + lch * 8] = vb;
    }
    __syncthreads();
    #pragma unroll
    for (int kk = 0; kk < 2; kk++) {
      const int kb = kk * 32 + (lane >> 4) * 8;
      bf16x8 af[4], bfr[4];
      #pragma unroll
      for (int mt = 0; mt < 4; mt++)
        af[mt] = *(const bf16x8*)&sA[(wr * 64 + mt * 16 + (lane & 15)) * 72 + kb];
      #pragma unroll
      for (int nt = 0; nt < 4; nt++)
        bfr[nt] = *(const bf16x8*)&sB[(wc * 64 + nt * 16 + (lane & 15)) * 72 + kb];
      #pragma unroll
      for (int mt = 0; mt < 4; mt++)
        #pragma unroll
        for (int nt = 0; nt < 4; nt++)
          acc[mt][nt] = __builtin_amdgcn_mfma_f32_16x16x32_bf16(
              af[mt], bfr[nt], acc[mt][nt], 0, 0, 0);
    }
    __syncthreads();
  }

  float gscale = 1.f;
  if (MODE == 2) {
    gscale = 1.f / (1.f + __expf(-bias[0]));
  }

  // C/D layout: col = lane&15, row = (lane>>4)*4 + reg
  const int r0 = bm * 128 + wr * 64 + ((lane >> 4) << 2);
  const int c0 = bn * 128 + wc * 64 + (lane & 15);
  #pragma unroll
  for (int mt = 0; mt < 4; mt++) {
    #pragma unroll
    for (int nt = 0; nt < 4; nt++) {
      const int col = c0 + nt * 16;
      #pragma unroll
      for (int i = 0; i < 4; i++) {
        const int row = r0 + mt * 16 + i;
        float v = acc[mt][nt][i];
        if (MODE == 0) {
          if (col < D_INNER) o0[(size_t)row * D_INNER + col] = f2b(v);
          else               o1[(size_t)row * D_INNER + (col - D_INNER)] = f2b(v);
        } else if (MODE == 1) {
          if (col < D_INNER) v = softplus_f(v + bias[col]);
          o0[(size_t)row * SDT + col] = f2b(v);
        } else {
          of[(size_t)row * D_MODEL + col] = v * gscale;
        }
      }
    }
  }
}

// ---- scan pass A: per chunk, per (b,d,n): P = prod A_bar, S = chunk inlet ----
__global__ __launch_bounds__(256) void scan_passA(
    const unsigned short* __restrict__ dtBC,
    const unsigned short* __restrict__ xs,
    const float* __restrict__ Alog,
    float* __restrict__ Pb, float* __restrict__ Sb)
{
  const int d = blockIdx.x * 256 + threadIdx.x;
  const int b = blockIdx.y;
  const int c = blockIdx.z;

  float a[NSTATE];
  #pragma unroll
  for (int n = 0; n < NSTATE; n++) a[n] = -__expf(Alog[d * NSTATE + n]);

  float P[NSTATE], S[NSTATE];
  #pragma unroll
  for (int n = 0; n < NSTATE; n++) { P[n] = 1.f; S[n] = 0.f; }

  __shared__ float sB[16][16];
  const size_t bL = (size_t)b * SEQ;
  const int t0c = c * CLEN;
  const int lt = threadIdx.x >> 4, ln = threadIdx.x & 15;

  for (int t0 = t0c; t0 < t0c + CLEN; t0 += 16) {
    __syncthreads();
    sB[lt][ln] = b2f(dtBC[(bL + t0 + lt) * SDT + 2048 + ln]);
    __syncthreads();
    for (int tt = 0; tt < 16; tt++) {
      const size_t rw = bL + t0 + tt;
      const float dt = b2f(dtBC[rw * SDT + d]);
      const float x  = b2f(xs[rw * D_INNER + d]);
      const float dtx = dt * x;
      #pragma unroll
      for (int n = 0; n < NSTATE; n++) {
        const float ab = __expf(dt * a[n]);   // dt>=0, a<0 => clamp(.,20) dead
        P[n] *= ab;
        S[n] = ab * S[n] + dtx * sB[tt][n];
      }
    }
  }
  const size_t base = (((size_t)c * BATCH + b) * D_INNER + d) * NSTATE;
  #pragma unroll
  for (int n = 0; n < NSTATE; n += 4) {
    *(f32x4*)&Pb[base + n] = (f32x4){P[n], P[n+1], P[n+2], P[n+3]};
    *(f32x4*)&Sb[base + n] = (f32x4){S[n], S[n+1], S[n+2], S[n+3]};
  }
}

// ---- scan pass B: sequential combine across chunks; Pb[c] <- h entering c ----
__global__ __launch_bounds__(256) void scan_passB(float* __restrict__ Pb,
                                                  const float* __restrict__ Sb)
{
  const size_t j = (size_t)blockIdx.x * 256 + threadIdx.x;  // (b,d,n) flat
  const size_t stride = (size_t)BATCH * D_INNER * NSTATE;
  float h = 0.f;
  for (int c = 0; c < NCHUNK; c++) {
    const size_t idx = (size_t)c * stride + j;
    const float p = Pb[idx];
    const float s = Sb[idx];
    Pb[idx] = h;
    h = p * h + s;
  }
}

// ---- scan pass C: re-scan chunk with true h0; y=(scan + x*D)*silu(z) ----
// NOTE: yb may alias zb (each thread reads z[rw,d] before writing y[rw,d]).
__global__ __launch_bounds__(256) void scan_passC(
    const unsigned short* __restrict__ dtBC,
    const unsigned short* __restrict__ xs,
    const unsigned short* __restrict__ zb,
    const float* __restrict__ Alog,
    const float* __restrict__ Dv,
    const float* __restrict__ Hb,
    unsigned short* __restrict__ yb)
{
  const int d = blockIdx.x * 256 + threadIdx.x;
  const int b = blockIdx.y;
  const int c = blockIdx.z;

  float a[NSTATE];
  #pragma unroll
  for (int n = 0; n < NSTATE; n++) a[n] = -__expf(Alog[d * NSTATE + n]);

  float h[NSTATE];
  const size_t base = (((size_t)c * BATCH + b) * D_INNER + d) * NSTATE;
  #pragma unroll
  for (int n = 0; n < NSTATE; n += 4) {
    f32x4 v = *(const f32x4*)&Hb[base + n];
    h[n] = v.x; h[n+1] = v.y; h[n+2] = v.z; h[n+3] = v.w;
  }
  const float Dd = Dv[d];

  __shared__ float sB[16][16];
  __shared__ float sC[16][16];
  const size_t bL = (size_t)b * SEQ;
  const int t0c = c * CLEN;
  const int lt = threadIdx.x >> 4, ln = threadIdx.x & 15;

  for (int t0 = t0c; t0 < t0c + CLEN; t0 += 16) {
    __syncthreads();
    {
      const size_t rwb = (bL + t0 + lt) * SDT + 2048;
      sB[lt][ln] = b2f(dtBC[rwb + ln]);
      sC[lt][ln] = b2f(dtBC[rwb + 16 + ln]);
    }
    __syncthreads();
    for (int tt = 0; tt < 16; tt++) {
      const size_t rw = bL + t0 + tt;
      const float dt = b2f(dtBC[rw * SDT + d]);
      const float x  = b2f(xs[rw * D_INNER + d]);
      const float z  = b2f(zb[rw * D_INNER + d]);
      const float dtx = dt * x;
      float y = 0.f;
      #pragma unroll
      for (int n = 0; n < NSTATE; n++) {
        const float ab = __expf(dt * a[n]);
        h[n] = ab * h[n] + dtx * sB[tt][n];
        y += h[n] * sC[tt][n];
      }
      y = (y + x * Dd) * (z / (1.f + __expf(-z)));   // +x*D, *silu(z)
      yb[rw * D_INNER + d] = f2b(y);
    }
  }
}

extern "C" void kernel_launch(void* const* d_in, const int* in_sizes, int n_in,
                              void* d_out, int out_size, void* d_ws, size_t ws_size,
                              hipStream_t stream)
{
  const float* x    = (const float*)d_in[0];   // (4,4096,1024)
  const float* Win  = (const float*)d_in[1];   // (4096,1024)
  const float* Alog = (const float*)d_in[2];   // (2048,16)
  const float* WB   = (const float*)d_in[3];   // (16,2048)
  const float* WC   = (const float*)d_in[4];   // (16,2048)
  const float* Wdt  = (const float*)d_in[5];   // (2048,2048)
  const float* bdt  = (const float*)d_in[6];   // (2048,)
  const float* Dv   = (const float*)d_in[7];   // (2048,)
  const float* gate = (const float*)d_in[8];   // (1,)
  const float* Wout = (const float*)d_in[9];   // (1024,2048)
  float* outp = (float*)d_out;                 // (4,4096,1024) f32

  // ---- d_ws layout: 200 MiB total ----
  char* ws = (char*)d_ws;
  unsigned short* xs    = (unsigned short*)(ws + 0);          // 16384x2048 bf16
  unsigned short* zy    = (unsigned short*)(ws + 67108864);   // z, later y (aliased)
  unsigned short* dtBC  = (unsigned short*)(ws + 134217728);  // 16384x2176 bf16
  unsigned short* Woutb = (unsigned short*)(ws + 205520896);  // 1024x2048 bf16 (4 MB)

  // ---- d_out (67.1 MB f32) doubles as scratch before final GEMM writes it ----
  char* ob = (char*)d_out;
  float* Pb = (float*)(ob + 0);                               // 16x4x2048x16 f32 (8 MB)
  float* Sb = (float*)(ob + 8388608);                         // (8 MB)
  unsigned short* Winb  = (unsigned short*)(ob + 16777216);   // 4096x1024 bf16 (8 MB)
  unsigned short* Wcatb = (unsigned short*)(ob + 25165824);   // 2176x2048 bf16 (8.9 MB)

  // prep: weight conversions
  cvt_f2b_kernel<<<4096, 256, 0, stream>>>(Win, Winb);        // 4.19M elems
  cvt_f2b_kernel<<<2048, 256, 0, stream>>>(Wout, Woutb);      // 2.10M elems
  concat_w_kernel<<<4352, 256, 0, stream>>>(Wdt, WB, WC, Wcatb);

  gemm_bt<0, 1><<<dim3(N1 / 128, MTOT / 128), 256, 0, stream>>>(
      (const void*)x, Winb, xs, zy, nullptr, nullptr, D_MODEL);
  gemm_bt<1, 0><<<dim3(NCAT / 128, MTOT / 128), 256, 0, stream>>>(
      (const void*)xs, Wcatb, dtBC, nullptr, nullptr, bdt, D_INNER);
  scan_passA<<<dim3(D_INNER / 256, BATCH, NCHUNK), 256, 0, stream>>>(
      dtBC, xs, Alog, Pb, Sb);
  scan_passB<<<(BATCH * D_INNER * NSTATE) / 256, 256, 0, stream>>>(Pb, Sb);
  scan_passC<<<dim3(D_INNER / 256, BATCH, NCHUNK), 256, 0, stream>>>(
      dtBC, xs, zy, Alog, Dv, Pb, zy);
  gemm_bt<2, 0><<<dim3(D_MODEL / 128, MTOT / 128), 256, 0, stream>>>(
      (const void*)zy, Woutb, nullptr, nullptr, outp, gate, D_INNER);
}

// Round 4
// 1147.996 us; speedup vs baseline: 1.0991x; 1.0991x over previous
//
#include <hip/hip_runtime.h>
#include <hip/hip_bf16.h>
#include <math.h>

#define D_MODEL 1024
#define D_INNER 2048
#define NSTATE  16
#define BATCH   4
#define SEQ     4096
#define MTOT    (BATCH*SEQ)      // 16384
#define SDT     2176             // dtBC row stride: 2048 dt | 16 B | 16 C | 96 pad
#define NCAT    2176             // padded N of concat weight
#define NCHUNK  16
#define CLEN    (SEQ/NCHUNK)     // 256
#define N1      (2*D_INNER)      // 4096

typedef __attribute__((ext_vector_type(8))) __bf16 bf16x8;
typedef __attribute__((ext_vector_type(4))) float f32x4;

__device__ __forceinline__ float b2f(unsigned short u){
  return __uint_as_float(((unsigned int)u) << 16);
}
__device__ __forceinline__ unsigned short f2b(float f){
  unsigned int u = __float_as_uint(f);
  u = (u + 0x7FFFu + ((u >> 16) & 1u)) >> 16;   // RNE
  return (unsigned short)u;
}
__device__ __forceinline__ float softplus_f(float x){
  float r = log1pf(__expf(-fabsf(x)));
  return x > 0.f ? x + r : r;
}

// async 16B global -> LDS (DMA; LDS dst = wave-uniform base + lane*16)
__device__ __forceinline__ void async16(unsigned short* lds, const unsigned short* g){
  __builtin_amdgcn_global_load_lds(
      (const __attribute__((address_space(1))) unsigned int*)g,
      (__attribute__((address_space(3))) unsigned int*)lds, 16, 0, 0);
}

// ---- f32 -> bf16 convert (4 elems/thread) ----
__global__ void cvt_f2b_kernel(const float* __restrict__ src,
                               unsigned short* __restrict__ dst){
  int i = (blockIdx.x * 256 + threadIdx.x) * 4;
  float4 v = *(const float4*)(src + i);
  *(ushort2*)(dst + i)     = (ushort2){f2b(v.x), f2b(v.y)};
  *(ushort2*)(dst + i + 2) = (ushort2){f2b(v.z), f2b(v.w)};
}

// ---- build Wcat(bf16) = [W_dt(2048); W_B(16); W_C(16); zeros(96)] : 2176x2048 ----
__global__ void concat_w_kernel(const float* __restrict__ Wdt,
                                const float* __restrict__ WB,
                                const float* __restrict__ WC,
                                unsigned short* __restrict__ Wcat){
  int idx = blockIdx.x * 256 + threadIdx.x;   // 4-elem granularity
  int row = idx >> 9;                         // 2048 cols = 512 quads/row
  int q   = idx & 511;
  float4 v;
  if      (row < 2048) v = *(const float4*)(Wdt + ((size_t)row * 2048 + q * 4));
  else if (row < 2064) v = *(const float4*)(WB  + ((size_t)(row - 2048) * 2048 + q * 4));
  else if (row < 2080) v = *(const float4*)(WC  + ((size_t)(row - 2064) * 2048 + q * 4));
  else                 v = make_float4(0.f, 0.f, 0.f, 0.f);
  unsigned short* p = Wcat + (size_t)idx * 4;
  *(ushort2*)(p)     = (ushort2){f2b(v.x), f2b(v.y)};
  *(ushort2*)(p + 2) = (ushort2){f2b(v.z), f2b(v.w)};
}

// ---- GEMM: C[M,N] = A[M,K] @ W[N,K]^T, bf16 MFMA, fp32 acc, fused epilogues ----
// Staging via global_load_lds width=16; LDS layout: [row][64k] stride 64 shorts,
// with chunk swizzle: physical 8-elem slot s of row r holds chunk s^(r&7).
// MODE 0: split cols -> o0=xs (n<2048), o1=z (n>=2048)   [bf16 out]
// MODE 1: n<2048 -> softplus(v + bias[n]); store stride SDT into o0=dtBC [bf16]
// MODE 2: v * sigmoid(bias[0]); store f32 into of (row stride D_MODEL)
template<int MODE>
__global__ __launch_bounds__(256) void gemm_bt(
    const unsigned short* __restrict__ A,
    const unsigned short* __restrict__ W,
    unsigned short* __restrict__ o0,
    unsigned short* __restrict__ o1,
    float* __restrict__ of,
    const float* __restrict__ bias,
    int K)
{
  const int bm = blockIdx.y, bn = blockIdx.x;
  const int tid = threadIdx.x;
  const int lane = tid & 63;
  const int w = tid >> 6;
  const int wr = w >> 1, wc = w & 1;

  __shared__ unsigned short sA[128 * 64];   // 16 KB, no padding (DMA-forced)
  __shared__ unsigned short sB[128 * 64];

  f32x4 acc[4][4];
  #pragma unroll
  for (int i = 0; i < 4; i++)
    #pragma unroll
    for (int j = 0; j < 4; j++) acc[i][j] = (f32x4){0.f, 0.f, 0.f, 0.f};

  // stager: wave w covers rows [32w,32w+32), 4 iters x 8 rows; lane -> (row,slot)
  const int rw8 = lane >> 3;                 // row within 8-row group
  const int ch  = (lane & 7) ^ rw8;          // global k-chunk fetched into slot lane&7
  const unsigned short* Ag = A + (size_t)(bm * 128 + w * 32 + rw8) * K + ch * 8;
  const unsigned short* Wg = W + (size_t)(bn * 128 + w * 32 + rw8) * K + ch * 8;
  unsigned short* sAw = &sA[(w * 32) * 64];
  unsigned short* sBw = &sB[(w * 32) * 64];

  const int m16 = lane & 15, q = lane >> 4;

  for (int k0 = 0; k0 < K; k0 += 64) {
    #pragma unroll
    for (int it = 0; it < 4; it++)
      async16(sAw + it * 8 * 64, Ag + (size_t)(it * 8) * K + k0);
    #pragma unroll
    for (int it = 0; it < 4; it++)
      async16(sBw + it * 8 * 64, Wg + (size_t)(it * 8) * K + k0);
    __syncthreads();   // drains vmcnt (compiler emits waitcnt before barrier)
    #pragma unroll
    for (int kk = 0; kk < 2; kk++) {
      bf16x8 af[4], bfr[4];
      #pragma unroll
      for (int mt = 0; mt < 4; mt++) {
        const int row = wr * 64 + mt * 16 + m16;
        af[mt] = *(const bf16x8*)&sA[row * 64 + (((kk * 4 + q) ^ (m16 & 7)) << 3)];
      }
      #pragma unroll
      for (int nt = 0; nt < 4; nt++) {
        const int row = wc * 64 + nt * 16 + m16;
        bfr[nt] = *(const bf16x8*)&sB[row * 64 + (((kk * 4 + q) ^ (m16 & 7)) << 3)];
      }
      #pragma unroll
      for (int mt = 0; mt < 4; mt++)
        #pragma unroll
        for (int nt = 0; nt < 4; nt++)
          acc[mt][nt] = __builtin_amdgcn_mfma_f32_16x16x32_bf16(
              af[mt], bfr[nt], acc[mt][nt], 0, 0, 0);
    }
    __syncthreads();
  }

  float gscale = 1.f;
  if (MODE == 2) gscale = 1.f / (1.f + __expf(-bias[0]));

  // C/D layout: col = lane&15, row = (lane>>4)*4 + reg
  const int r0 = bm * 128 + wr * 64 + (q << 2);
  const int c0 = bn * 128 + wc * 64 + m16;
  #pragma unroll
  for (int mt = 0; mt < 4; mt++) {
    #pragma unroll
    for (int nt = 0; nt < 4; nt++) {
      const int col = c0 + nt * 16;
      #pragma unroll
      for (int i = 0; i < 4; i++) {
        const int row = r0 + mt * 16 + i;
        float v = acc[mt][nt][i];
        if (MODE == 0) {
          if (col < D_INNER) o0[(size_t)row * D_INNER + col] = f2b(v);
          else               o1[(size_t)row * D_INNER + (col - D_INNER)] = f2b(v);
        } else if (MODE == 1) {
          if (col < D_INNER) v = softplus_f(v + bias[col]);
          o0[(size_t)row * SDT + col] = f2b(v);
        } else {
          of[(size_t)row * D_MODEL + col] = v * gscale;
        }
      }
    }
  }
}

// ---- scan pass A: per chunk, per (b,d,n): P = prod A_bar, S = chunk inlet ----
__global__ __launch_bounds__(256) void scan_passA(
    const unsigned short* __restrict__ dtBC,
    const unsigned short* __restrict__ xs,
    const float* __restrict__ Alog,
    float* __restrict__ Pb, float* __restrict__ Sb)
{
  const int d = blockIdx.x * 256 + threadIdx.x;
  const int b = blockIdx.y;
  const int c = blockIdx.z;

  float a[NSTATE];
  #pragma unroll
  for (int n = 0; n < NSTATE; n++) a[n] = -__expf(Alog[d * NSTATE + n]);

  float P[NSTATE], S[NSTATE];
  #pragma unroll
  for (int n = 0; n < NSTATE; n++) { P[n] = 1.f; S[n] = 0.f; }

  __shared__ float sB[16][16];
  const size_t bL = (size_t)b * SEQ;
  const int t0c = c * CLEN;
  const int lt = threadIdx.x >> 4, ln = threadIdx.x & 15;

  for (int t0 = t0c; t0 < t0c + CLEN; t0 += 16) {
    __syncthreads();
    sB[lt][ln] = b2f(dtBC[(bL + t0 + lt) * SDT + 2048 + ln]);
    __syncthreads();
    for (int tt = 0; tt < 16; tt++) {
      const size_t rw = bL + t0 + tt;
      const float dt = b2f(dtBC[rw * SDT + d]);
      const float x  = b2f(xs[rw * D_INNER + d]);
      const float dtx = dt * x;
      #pragma unroll
      for (int n = 0; n < NSTATE; n++) {
        const float ab = __expf(dt * a[n]);   // dt>=0, a<0 => clamp(.,20) dead
        P[n] *= ab;
        S[n] = ab * S[n] + dtx * sB[tt][n];
      }
    }
  }
  const size_t base = (((size_t)c * BATCH + b) * D_INNER + d) * NSTATE;
  #pragma unroll
  for (int n = 0; n < NSTATE; n += 4) {
    *(f32x4*)&Pb[base + n] = (f32x4){P[n], P[n+1], P[n+2], P[n+3]};
    *(f32x4*)&Sb[base + n] = (f32x4){S[n], S[n+1], S[n+2], S[n+3]};
  }
}

// ---- scan pass B: sequential combine across chunks; Pb[c] <- h entering c ----
__global__ __launch_bounds__(256) void scan_passB(float* __restrict__ Pb,
                                                  const float* __restrict__ Sb)
{
  const size_t j = (size_t)blockIdx.x * 256 + threadIdx.x;  // (b,d,n) flat
  const size_t stride = (size_t)BATCH * D_INNER * NSTATE;
  float h = 0.f;
  for (int c = 0; c < NCHUNK; c++) {
    const size_t idx = (size_t)c * stride + j;
    const float p = Pb[idx];
    const float s = Sb[idx];
    Pb[idx] = h;
    h = p * h + s;
  }
}

// ---- scan pass C: re-scan chunk with true h0; y=(scan + x*D)*silu(z) ----
// NOTE: yb may alias zb (each thread reads z[rw,d] before writing y[rw,d]).
__global__ __launch_bounds__(256) void scan_passC(
    const unsigned short* __restrict__ dtBC,
    const unsigned short* __restrict__ xs,
    const unsigned short* __restrict__ zb,
    const float* __restrict__ Alog,
    const float* __restrict__ Dv,
    const float* __restrict__ Hb,
    unsigned short* __restrict__ yb)
{
  const int d = blockIdx.x * 256 + threadIdx.x;
  const int b = blockIdx.y;
  const int c = blockIdx.z;

  float a[NSTATE];
  #pragma unroll
  for (int n = 0; n < NSTATE; n++) a[n] = -__expf(Alog[d * NSTATE + n]);

  float h[NSTATE];
  const size_t base = (((size_t)c * BATCH + b) * D_INNER + d) * NSTATE;
  #pragma unroll
  for (int n = 0; n < NSTATE; n += 4) {
    f32x4 v = *(const f32x4*)&Hb[base + n];
    h[n] = v.x; h[n+1] = v.y; h[n+2] = v.z; h[n+3] = v.w;
  }
  const float Dd = Dv[d];

  __shared__ float sB[16][16];
  __shared__ float sC[16][16];
  const size_t bL = (size_t)b * SEQ;
  const int t0c = c * CLEN;
  const int lt = threadIdx.x >> 4, ln = threadIdx.x & 15;

  for (int t0 = t0c; t0 < t0c + CLEN; t0 += 16) {
    __syncthreads();
    {
      const size_t rwb = (bL + t0 + lt) * SDT + 2048;
      sB[lt][ln] = b2f(dtBC[rwb + ln]);
      sC[lt][ln] = b2f(dtBC[rwb + 16 + ln]);
    }
    __syncthreads();
    for (int tt = 0; tt < 16; tt++) {
      const size_t rw = bL + t0 + tt;
      const float dt = b2f(dtBC[rw * SDT + d]);
      const float x  = b2f(xs[rw * D_INNER + d]);
      const float z  = b2f(zb[rw * D_INNER + d]);
      const float dtx = dt * x;
      float y = 0.f;
      #pragma unroll
      for (int n = 0; n < NSTATE; n++) {
        const float ab = __expf(dt * a[n]);
        h[n] = ab * h[n] + dtx * sB[tt][n];
        y += h[n] * sC[tt][n];
      }
      y = (y + x * Dd) * (z / (1.f + __expf(-z)));   // +x*D, *silu(z)
      yb[rw * D_INNER + d] = f2b(y);
    }
  }
}

extern "C" void kernel_launch(void* const* d_in, const int* in_sizes, int n_in,
                              void* d_out, int out_size, void* d_ws, size_t ws_size,
                              hipStream_t stream)
{
  const float* x    = (const float*)d_in[0];   // (4,4096,1024)
  const float* Win  = (const float*)d_in[1];   // (4096,1024)
  const float* Alog = (const float*)d_in[2];   // (2048,16)
  const float* WB   = (const float*)d_in[3];   // (16,2048)
  const float* WC   = (const float*)d_in[4];   // (16,2048)
  const float* Wdt  = (const float*)d_in[5];   // (2048,2048)
  const float* bdt  = (const float*)d_in[6];   // (2048,)
  const float* Dv   = (const float*)d_in[7];   // (2048,)
  const float* gate = (const float*)d_in[8];   // (1,)
  const float* Wout = (const float*)d_in[9];   // (1024,2048)
  float* outp = (float*)d_out;                 // (4,4096,1024) f32

  // ---- d_ws layout: 208 MiB total ----
  char* ws = (char*)d_ws;
  unsigned short* xs    = (unsigned short*)(ws + 0);          // 16384x2048 bf16
  unsigned short* zy    = (unsigned short*)(ws + 67108864);   // z, later y (aliased)
  unsigned short* dtBC  = (unsigned short*)(ws + 134217728);  // 16384x2176 bf16
  unsigned short* Winb  = (unsigned short*)(ws + 205520896);  // 4096x1024 bf16 (8 MB)
  unsigned short* Woutb = (unsigned short*)(ws + 213909504);  // 1024x2048 bf16 (4 MB)

  // ---- d_out (67.1 MB f32) doubles as scratch before final GEMM writes it ----
  char* ob = (char*)d_out;
  float* Pb = (float*)(ob + 0);                               // 16x4x2048x16 f32 (8 MB)
  float* Sb = (float*)(ob + 8388608);                         // (8 MB)
  unsigned short* Wcatb = (unsigned short*)(ob + 16777216);   // 2176x2048 bf16 (8.9 MB)
  unsigned short* xb    = (unsigned short*)(ob + 33554432);   // 16384x1024 bf16 (33.5 MB)

  // prep: input + weight conversions to bf16
  cvt_f2b_kernel<<<16384, 256, 0, stream>>>(x, xb);
  cvt_f2b_kernel<<<4096, 256, 0, stream>>>(Win, Winb);
  cvt_f2b_kernel<<<2048, 256, 0, stream>>>(Wout, Woutb);
  concat_w_kernel<<<4352, 256, 0, stream>>>(Wdt, WB, WC, Wcatb);

  gemm_bt<0><<<dim3(N1 / 128, MTOT / 128), 256, 0, stream>>>(
      xb, Winb, xs, zy, nullptr, nullptr, D_MODEL);
  gemm_bt<1><<<dim3(NCAT / 128, MTOT / 128), 256, 0, stream>>>(
      xs, Wcatb, dtBC, nullptr, nullptr, bdt, D_INNER);
  scan_passA<<<dim3(D_INNER / 256, BATCH, NCHUNK), 256, 0, stream>>>(
      dtBC, xs, Alog, Pb, Sb);
  scan_passB<<<(BATCH * D_INNER * NSTATE) / 256, 256, 0, stream>>>(Pb, Sb);
  scan_passC<<<dim3(D_INNER / 256, BATCH, NCHUNK), 256, 0, stream>>>(
      dtBC, xs, zy, Alog, Dv, Pb, zy);
  gemm_bt<2><<<dim3(D_MODEL / 128, MTOT / 128), 256, 0, stream>>>(
      zy, Woutb, nullptr, nullptr, outp, gate, D_INNER);
}

// Round 5
// 1129.298 us; speedup vs baseline: 1.1173x; 1.0166x over previous
//
#include <hip/hip_runtime.h>
#include <hip/hip_bf16.h>
#include <math.h>

#define D_MODEL 1024
#define D_INNER 2048
#define NSTATE  16
#define BATCH   4
#define SEQ     4096
#define MTOT    (BATCH*SEQ)      // 16384
#define SDT     2176             // dtBC row stride: 2048 dt | 16 B | 16 C | 96 pad
#define NCAT    2176             // padded N of concat weight
#define NCHUNK  16
#define CLEN    (SEQ/NCHUNK)     // 256
#define N1      (2*D_INNER)      // 4096

typedef __attribute__((ext_vector_type(8))) __bf16 bf16x8;
typedef __attribute__((ext_vector_type(4))) float f32x4;

__device__ __forceinline__ float b2f(unsigned short u){
  return __uint_as_float(((unsigned int)u) << 16);
}
__device__ __forceinline__ unsigned short f2b(float f){
  unsigned int u = __float_as_uint(f);
  u = (u + 0x7FFFu + ((u >> 16) & 1u)) >> 16;   // RNE
  return (unsigned short)u;
}
__device__ __forceinline__ float softplus_f(float x){
  float r = log1pf(__expf(-fabsf(x)));
  return x > 0.f ? x + r : r;
}

// async 16B global -> LDS (DMA; LDS dst = wave-uniform base + lane*16)
__device__ __forceinline__ void async16(unsigned short* lds, const unsigned short* g){
  __builtin_amdgcn_global_load_lds(
      (const __attribute__((address_space(1))) unsigned int*)g,
      (__attribute__((address_space(3))) unsigned int*)lds, 16, 0, 0);
}

// ---- f32 -> bf16 convert (4 elems/thread) ----
__global__ void cvt_f2b_kernel(const float* __restrict__ src,
                               unsigned short* __restrict__ dst){
  int i = (blockIdx.x * 256 + threadIdx.x) * 4;
  float4 v = *(const float4*)(src + i);
  *(ushort2*)(dst + i)     = (ushort2){f2b(v.x), f2b(v.y)};
  *(ushort2*)(dst + i + 2) = (ushort2){f2b(v.z), f2b(v.w)};
}

// ---- build Wcat(bf16) = [W_dt(2048); W_B(16); W_C(16); zeros(96)] : 2176x2048 ----
__global__ void concat_w_kernel(const float* __restrict__ Wdt,
                                const float* __restrict__ WB,
                                const float* __restrict__ WC,
                                unsigned short* __restrict__ Wcat){
  int idx = blockIdx.x * 256 + threadIdx.x;   // 4-elem granularity
  int row = idx >> 9;                         // 2048 cols = 512 quads/row
  int q   = idx & 511;
  float4 v;
  if      (row < 2048) v = *(const float4*)(Wdt + ((size_t)row * 2048 + q * 4));
  else if (row < 2064) v = *(const float4*)(WB  + ((size_t)(row - 2048) * 2048 + q * 4));
  else if (row < 2080) v = *(const float4*)(WC  + ((size_t)(row - 2064) * 2048 + q * 4));
  else                 v = make_float4(0.f, 0.f, 0.f, 0.f);
  unsigned short* p = Wcat + (size_t)idx * 4;
  *(ushort2*)(p)     = (ushort2){f2b(v.x), f2b(v.y)};
  *(ushort2*)(p + 2) = (ushort2){f2b(v.z), f2b(v.w)};
}

// ---- GEMM: C[M,N] = A[M,K] @ W[N,K]^T, bf16 MFMA, fp32 acc, fused epilogues ----
// Double-buffered LDS + global_load_lds(16B) + raw s_barrier / fine vmcnt:
// prefetch of tile k+1 stays in flight across the barrier (no vmcnt(0) drain).
// LDS layout per buffer: [row][64k], chunk swizzle: slot s of row r holds s^(r&7).
// MODE 0: split cols -> o0=xs (n<2048), o1=z (n>=2048)   [bf16 out]
// MODE 1: n<2048 -> softplus(v + bias[n]); store stride SDT into o0=dtBC [bf16]
// MODE 2: v * sigmoid(bias[0]); store f32 into of (row stride D_MODEL)
template<int MODE>
__global__ __launch_bounds__(256, 2) void gemm_bt(
    const unsigned short* __restrict__ A,
    const unsigned short* __restrict__ W,
    unsigned short* __restrict__ o0,
    unsigned short* __restrict__ o1,
    float* __restrict__ of,
    const float* __restrict__ bias,
    int K)
{
  const int bm = blockIdx.y, bn = blockIdx.x;
  const int tid = threadIdx.x;
  const int lane = tid & 63;
  const int w = tid >> 6;
  const int wr = w >> 1, wc = w & 1;

  __shared__ unsigned short sAd[2][128 * 64];   // 2 x 16 KB
  __shared__ unsigned short sBd[2][128 * 64];   // 2 x 16 KB

  f32x4 acc[4][4];
  #pragma unroll
  for (int i = 0; i < 4; i++)
    #pragma unroll
    for (int j = 0; j < 4; j++) acc[i][j] = (f32x4){0.f, 0.f, 0.f, 0.f};

  // stager: wave w covers rows [32w,32w+32), 4 iters x 8 rows; lane -> (row,slot)
  const int rw8 = lane >> 3;                 // row within 8-row group
  const int ch  = (lane & 7) ^ rw8;          // global k-chunk fetched into slot lane&7
  const unsigned short* Ag = A + (size_t)(bm * 128 + w * 32 + rw8) * K + ch * 8;
  const unsigned short* Wg = W + (size_t)(bn * 128 + w * 32 + rw8) * K + ch * 8;

  const int m16 = lane & 15, q = lane >> 4;

  // prologue: stage k0=0 into buffer 0
  #pragma unroll
  for (int it = 0; it < 4; it++)
    async16(&sAd[0][(w * 32 + it * 8) * 64], Ag + (size_t)(it * 8) * K);
  #pragma unroll
  for (int it = 0; it < 4; it++)
    async16(&sBd[0][(w * 32 + it * 8) * 64], Wg + (size_t)(it * 8) * K);

  int cur = 0;
  for (int k0 = 0; k0 < K; k0 += 64) {
    const int nxt = cur ^ 1;
    if (k0 + 64 < K) {
      #pragma unroll
      for (int it = 0; it < 4; it++)
        async16(&sAd[nxt][(w * 32 + it * 8) * 64], Ag + (size_t)(it * 8) * K + k0 + 64);
      #pragma unroll
      for (int it = 0; it < 4; it++)
        async16(&sBd[nxt][(w * 32 + it * 8) * 64], Wg + (size_t)(it * 8) * K + k0 + 64);
      asm volatile("s_waitcnt vmcnt(8)" ::: "memory");   // cur's 8 loads done; nxt's stay in flight
    } else {
      asm volatile("s_waitcnt vmcnt(0)" ::: "memory");
    }
    asm volatile("s_barrier" ::: "memory");              // all waves' cur data ready

    const unsigned short* pA = sAd[cur];
    const unsigned short* pB = sBd[cur];
    #pragma unroll
    for (int kk = 0; kk < 2; kk++) {
      bf16x8 af[4], bfr[4];
      #pragma unroll
      for (int mt = 0; mt < 4; mt++) {
        const int row = wr * 64 + mt * 16 + m16;
        af[mt] = *(const bf16x8*)&pA[row * 64 + (((kk * 4 + q) ^ (m16 & 7)) << 3)];
      }
      #pragma unroll
      for (int nt = 0; nt < 4; nt++) {
        const int row = wc * 64 + nt * 16 + m16;
        bfr[nt] = *(const bf16x8*)&pB[row * 64 + (((kk * 4 + q) ^ (m16 & 7)) << 3)];
      }
      #pragma unroll
      for (int mt = 0; mt < 4; mt++)
        #pragma unroll
        for (int nt = 0; nt < 4; nt++)
          acc[mt][nt] = __builtin_amdgcn_mfma_f32_16x16x32_bf16(
              af[mt], bfr[nt], acc[mt][nt], 0, 0, 0);
    }
    asm volatile("s_waitcnt lgkmcnt(0)" ::: "memory");   // my reads of cur retired
    asm volatile("s_barrier" ::: "memory");              // everyone's reads done -> cur reusable
    cur = nxt;
  }

  float gscale = 1.f;
  if (MODE == 2) gscale = 1.f / (1.f + __expf(-bias[0]));

  // C/D layout: col = lane&15, row = (lane>>4)*4 + reg
  const int r0 = bm * 128 + wr * 64 + (q << 2);
  const int c0 = bn * 128 + wc * 64 + m16;
  #pragma unroll
  for (int mt = 0; mt < 4; mt++) {
    #pragma unroll
    for (int nt = 0; nt < 4; nt++) {
      const int col = c0 + nt * 16;
      #pragma unroll
      for (int i = 0; i < 4; i++) {
        const int row = r0 + mt * 16 + i;
        float v = acc[mt][nt][i];
        if (MODE == 0) {
          if (col < D_INNER) o0[(size_t)row * D_INNER + col] = f2b(v);
          else               o1[(size_t)row * D_INNER + (col - D_INNER)] = f2b(v);
        } else if (MODE == 1) {
          if (col < D_INNER) v = softplus_f(v + bias[col]);
          o0[(size_t)row * SDT + col] = f2b(v);
        } else {
          of[(size_t)row * D_MODEL + col] = v * gscale;
        }
      }
    }
  }
}

// ---- scan pass A: per chunk, per (b,d,n): P = prod A_bar, S = chunk inlet ----
__global__ __launch_bounds__(256) void scan_passA(
    const unsigned short* __restrict__ dtBC,
    const unsigned short* __restrict__ xs,
    const float* __restrict__ Alog,
    float* __restrict__ Pb, float* __restrict__ Sb)
{
  const int d = blockIdx.x * 256 + threadIdx.x;
  const int b = blockIdx.y;
  const int c = blockIdx.z;

  float a[NSTATE];
  #pragma unroll
  for (int n = 0; n < NSTATE; n++) a[n] = -__expf(Alog[d * NSTATE + n]);

  float P[NSTATE], S[NSTATE];
  #pragma unroll
  for (int n = 0; n < NSTATE; n++) { P[n] = 1.f; S[n] = 0.f; }

  __shared__ float sB[16][16];
  const size_t bL = (size_t)b * SEQ;
  const int t0c = c * CLEN;
  const int lt = threadIdx.x >> 4, ln = threadIdx.x & 15;

  for (int t0 = t0c; t0 < t0c + CLEN; t0 += 16) {
    __syncthreads();
    sB[lt][ln] = b2f(dtBC[(bL + t0 + lt) * SDT + 2048 + ln]);
    __syncthreads();
    for (int tt = 0; tt < 16; tt++) {
      const size_t rw = bL + t0 + tt;
      const float dt = b2f(dtBC[rw * SDT + d]);
      const float x  = b2f(xs[rw * D_INNER + d]);
      const float dtx = dt * x;
      #pragma unroll
      for (int n = 0; n < NSTATE; n++) {
        const float ab = __expf(dt * a[n]);   // dt>=0, a<0 => clamp(.,20) dead
        P[n] *= ab;
        S[n] = ab * S[n] + dtx * sB[tt][n];
      }
    }
  }
  const size_t base = (((size_t)c * BATCH + b) * D_INNER + d) * NSTATE;
  #pragma unroll
  for (int n = 0; n < NSTATE; n += 4) {
    *(f32x4*)&Pb[base + n] = (f32x4){P[n], P[n+1], P[n+2], P[n+3]};
    *(f32x4*)&Sb[base + n] = (f32x4){S[n], S[n+1], S[n+2], S[n+3]};
  }
}

// ---- scan pass B: sequential combine across chunks; Pb[c] <- h entering c ----
__global__ __launch_bounds__(256) void scan_passB(float* __restrict__ Pb,
                                                  const float* __restrict__ Sb)
{
  const size_t j = (size_t)blockIdx.x * 256 + threadIdx.x;  // (b,d,n) flat
  const size_t stride = (size_t)BATCH * D_INNER * NSTATE;
  float h = 0.f;
  for (int c = 0; c < NCHUNK; c++) {
    const size_t idx = (size_t)c * stride + j;
    const float p = Pb[idx];
    const float s = Sb[idx];
    Pb[idx] = h;
    h = p * h + s;
  }
}

// ---- scan pass C: re-scan chunk with true h0; y=(scan + x*D)*silu(z) ----
// NOTE: yb may alias zb (each thread reads z[rw,d] before writing y[rw,d]).
__global__ __launch_bounds__(256) void scan_passC(
    const unsigned short* __restrict__ dtBC,
    const unsigned short* __restrict__ xs,
    const unsigned short* __restrict__ zb,
    const float* __restrict__ Alog,
    const float* __restrict__ Dv,
    const float* __restrict__ Hb,
    unsigned short* __restrict__ yb)
{
  const int d = blockIdx.x * 256 + threadIdx.x;
  const int b = blockIdx.y;
  const int c = blockIdx.z;

  float a[NSTATE];
  #pragma unroll
  for (int n = 0; n < NSTATE; n++) a[n] = -__expf(Alog[d * NSTATE + n]);

  float h[NSTATE];
  const size_t base = (((size_t)c * BATCH + b) * D_INNER + d) * NSTATE;
  #pragma unroll
  for (int n = 0; n < NSTATE; n += 4) {
    f32x4 v = *(const f32x4*)&Hb[base + n];
    h[n] = v.x; h[n+1] = v.y; h[n+2] = v.z; h[n+3] = v.w;
  }
  const float Dd = Dv[d];

  __shared__ float sB[16][16];
  __shared__ float sC[16][16];
  const size_t bL = (size_t)b * SEQ;
  const int t0c = c * CLEN;
  const int lt = threadIdx.x >> 4, ln = threadIdx.x & 15;

  for (int t0 = t0c; t0 < t0c + CLEN; t0 += 16) {
    __syncthreads();
    {
      const size_t rwb = (bL + t0 + lt) * SDT + 2048;
      sB[lt][ln] = b2f(dtBC[rwb + ln]);
      sC[lt][ln] = b2f(dtBC[rwb + 16 + ln]);
    }
    __syncthreads();
    for (int tt = 0; tt < 16; tt++) {
      const size_t rw = bL + t0 + tt;
      const float dt = b2f(dtBC[rw * SDT + d]);
      const float x  = b2f(xs[rw * D_INNER + d]);
      const float z  = b2f(zb[rw * D_INNER + d]);
      const float dtx = dt * x;
      float y = 0.f;
      #pragma unroll
      for (int n = 0; n < NSTATE; n++) {
        const float ab = __expf(dt * a[n]);
        h[n] = ab * h[n] + dtx * sB[tt][n];
        y += h[n] * sC[tt][n];
      }
      y = (y + x * Dd) * (z / (1.f + __expf(-z)));   // +x*D, *silu(z)
      yb[rw * D_INNER + d] = f2b(y);
    }
  }
}

extern "C" void kernel_launch(void* const* d_in, const int* in_sizes, int n_in,
                              void* d_out, int out_size, void* d_ws, size_t ws_size,
                              hipStream_t stream)
{
  const float* x    = (const float*)d_in[0];   // (4,4096,1024)
  const float* Win  = (const float*)d_in[1];   // (4096,1024)
  const float* Alog = (const float*)d_in[2];   // (2048,16)
  const float* WB   = (const float*)d_in[3];   // (16,2048)
  const float* WC   = (const float*)d_in[4];   // (16,2048)
  const float* Wdt  = (const float*)d_in[5];   // (2048,2048)
  const float* bdt  = (const float*)d_in[6];   // (2048,)
  const float* Dv   = (const float*)d_in[7];   // (2048,)
  const float* gate = (const float*)d_in[8];   // (1,)
  const float* Wout = (const float*)d_in[9];   // (1024,2048)
  float* outp = (float*)d_out;                 // (4,4096,1024) f32

  // ---- d_ws layout: 208 MiB total ----
  char* ws = (char*)d_ws;
  unsigned short* xs    = (unsigned short*)(ws + 0);          // 16384x2048 bf16
  unsigned short* zy    = (unsigned short*)(ws + 67108864);   // z, later y (aliased)
  unsigned short* dtBC  = (unsigned short*)(ws + 134217728);  // 16384x2176 bf16
  unsigned short* Winb  = (unsigned short*)(ws + 205520896);  // 4096x1024 bf16 (8 MB)
  unsigned short* Woutb = (unsigned short*)(ws + 213909504);  // 1024x2048 bf16 (4 MB)

  // ---- d_out (67.1 MB f32) doubles as scratch before final GEMM writes it ----
  char* ob = (char*)d_out;
  float* Pb = (float*)(ob + 0);                               // 16x4x2048x16 f32 (8 MB)
  float* Sb = (float*)(ob + 8388608);                         // (8 MB)
  unsigned short* Wcatb = (unsigned short*)(ob + 16777216);   // 2176x2048 bf16 (8.9 MB)
  unsigned short* xb    = (unsigned short*)(ob + 33554432);   // 16384x1024 bf16 (33.5 MB)

  // prep: input + weight conversions to bf16
  cvt_f2b_kernel<<<16384, 256, 0, stream>>>(x, xb);
  cvt_f2b_kernel<<<4096, 256, 0, stream>>>(Win, Winb);
  cvt_f2b_kernel<<<2048, 256, 0, stream>>>(Wout, Woutb);
  concat_w_kernel<<<4352, 256, 0, stream>>>(Wdt, WB, WC, Wcatb);

  gemm_bt<0><<<dim3(N1 / 128, MTOT / 128), 256, 0, stream>>>(
      xb, Winb, xs, zy, nullptr, nullptr, D_MODEL);
  gemm_bt<1><<<dim3(NCAT / 128, MTOT / 128), 256, 0, stream>>>(
      xs, Wcatb, dtBC, nullptr, nullptr, bdt, D_INNER);
  scan_passA<<<dim3(D_INNER / 256, BATCH, NCHUNK), 256, 0, stream>>>(
      dtBC, xs, Alog, Pb, Sb);
  scan_passB<<<(BATCH * D_INNER * NSTATE) / 256, 256, 0, stream>>>(Pb, Sb);
  scan_passC<<<dim3(D_INNER / 256, BATCH, NCHUNK), 256, 0, stream>>>(
      dtBC, xs, zy, Alog, Dv, Pb, zy);
  gemm_bt<2><<<dim3(D_MODEL / 128, MTOT / 128), 256, 0, stream>>>(
      zy, Woutb, nullptr, nullptr, outp, gate, D_INNER);
}